// Round 19
// baseline (251.878 us; speedup 1.0000x reference)
//
#include <hip/hip_runtime.h>

typedef short bf16x8 __attribute__((ext_vector_type(8)));
typedef float f32x4 __attribute__((ext_vector_type(4)));
typedef unsigned int u32;
typedef unsigned short u16;

#define NIT 21
#define SMIN 1e-33f
#define LDSCOL 136   // padded k-stride in u16 (272B, 16B-aligned) — r16/r18-proven

static __device__ __forceinline__ u16 f2bf(float f) {   // RNE pack (validated r8/r14/r16/r18)
    u32 u = __float_as_uint(f);
    u = (u + 0x7fffu + ((u >> 16) & 1u)) >> 16;
    return (u16)u;
}
static __device__ __forceinline__ float bf2f(u16 h) {
    return __uint_as_float(((u32)h) << 16);
}

// MFMA Sinkhorn, r18 dataflow (150us validated), TWO matrices per 512-thread
// block. r18 post-mortem: barrier/dependency-bound (resource floors ~65us vs
// wall 150; extra TLP bought 2%). Here each wave owns one 16-row tile of BOTH
// matrices (af0/af1 A-operand fragments in regs); col/row phases interleave
// the two matrices' independent 4-deep MFMA chains (they fill each other's
// latency), and each barrier now covers 2 matrices of work. Per-matrix
// numerics/byte-layout identical to r18 (row-max shift, bf16 E, E^T LDS image,
// lazy rcp factors, m89 C/D layout, shared (lane,slot)->k map so HW k-perm
// cancels). LDS 2x34.8KB ~ 70.7KB -> 2 blocks/CU.
__global__ __launch_bounds__(512)
void sinkhorn_kernel(const float* __restrict__ in, float* __restrict__ out) {
    const int t  = threadIdx.x;
    const int w  = t >> 6;         // wave 0..7
    const int lg = (t >> 4) & 3;   // k-group within wave
    const int ln = t & 15;         // m/n within tile
    const int M  = w * 16 + ln;    // this lane's matrix row (and col-tile n)
    const size_t mat0 = (size_t)(2 * blockIdx.x) << 14;
    const float S = 36.067376022224085f;   // (1/0.04)*log2(e)

    __shared__ __align__(16) u16 Ecm[2][128 * LDSCOL];   // E^T per matrix
    __shared__ __align__(16) u16 a_lds[2][128];
    __shared__ __align__(16) u16 b_lds[2][128];

    bf16x8 af[2][4];   // af[pm][c] = E_pm[M][c*32+lg*8 ..+7]

    // ---- init per matrix: load, rowmax, E = bf16(2^((x-m)*S)); regs + E^T image ----
#pragma unroll
    for (int pm = 0; pm < 2; ++pm) {
        const float* src = in + mat0 + ((size_t)pm << 14) + (size_t)M * 128 + lg * 8;
        float v[4][8];
        float m = -3.4e38f;
#pragma unroll
        for (int c = 0; c < 4; ++c) {
            float4 f0 = *(const float4*)(src + c * 32);
            float4 f1 = *(const float4*)(src + c * 32 + 4);
            v[c][0] = f0.x; v[c][1] = f0.y; v[c][2] = f0.z; v[c][3] = f0.w;
            v[c][4] = f1.x; v[c][5] = f1.y; v[c][6] = f1.z; v[c][7] = f1.w;
#pragma unroll
            for (int j = 0; j < 8; ++j) m = fmaxf(m, v[c][j]);
        }
        m = fmaxf(m, __shfl_xor(m, 16));   // row M held by lanes {ln,+16,+32,+48}
        m = fmaxf(m, __shfl_xor(m, 32));
        const float nms = -m * S;
        float s = 0.f;
#pragma unroll
        for (int c = 0; c < 4; ++c) {
            bf16x8 fr;
#pragma unroll
            for (int j = 0; j < 8; ++j) {
                float e = __builtin_amdgcn_exp2f(fmaf(v[c][j], S, nms));
                s += e;
                fr[j] = (short)f2bf(e);
            }
            af[pm][c] = fr;
#pragma unroll
            for (int j = 0; j < 8; ++j)     // one-time transposed scalar writes
                Ecm[pm][(c * 32 + lg * 8 + j) * LDSCOL + M] = (u16)fr[j];
        }
        s += __shfl_xor(s, 16);
        s += __shfl_xor(s, 32);
        if (lg == 0) a_lds[pm][M] = f2bf(__builtin_amdgcn_rcpf(fmaxf(s, SMIN)));
    }
    __syncthreads();

    const f32x4 z4 = {0.f, 0.f, 0.f, 0.f};

#pragma unroll 1
    for (int it = 0; it < NIT; ++it) {
        // ---- col phases (both matrices, independent chains interleaved) ----
        f32x4 acc0 = z4, acc1 = z4;
#pragma unroll
        for (int c = 0; c < 4; ++c) {
            const int kb = c * 32 + lg * 8;
            bf16x8 a0 = *(const bf16x8*)&a_lds[0][kb];
            bf16x8 e0 = *(const bf16x8*)&Ecm[0][M * LDSCOL + kb];
            bf16x8 a1 = *(const bf16x8*)&a_lds[1][kb];
            bf16x8 e1 = *(const bf16x8*)&Ecm[1][M * LDSCOL + kb];
            acc0 = __builtin_amdgcn_mfma_f32_16x16x32_bf16(a0, e0, acc0, 0, 0, 0);
            acc1 = __builtin_amdgcn_mfma_f32_16x16x32_bf16(a1, e1, acc1, 0, 0, 0);
        }
        if (lg == 0) {   // D rows identical; lane holds col n=ln of its tile (m89)
            b_lds[0][M] = f2bf(__builtin_amdgcn_rcpf(fmaxf(acc0[0], SMIN)));
            b_lds[1][M] = f2bf(__builtin_amdgcn_rcpf(fmaxf(acc1[0], SMIN)));
        }
        __syncthreads();

        // ---- row phases (both matrices) ----
        if (it < NIT - 1) {
            f32x4 r0 = z4, r1 = z4;
#pragma unroll
            for (int c = 0; c < 4; ++c) {
                const int kb = c * 32 + lg * 8;
                bf16x8 b0 = *(const bf16x8*)&b_lds[0][kb];
                bf16x8 b1 = *(const bf16x8*)&b_lds[1][kb];
                r0 = __builtin_amdgcn_mfma_f32_16x16x32_bf16(af[0][c], b0, r0, 0, 0, 0);
                r1 = __builtin_amdgcn_mfma_f32_16x16x32_bf16(af[1][c], b1, r1, 0, 0, 0);
            }
            if (ln == 0) {   // D cols identical; lane holds tile rows lg*4+r
#pragma unroll
                for (int r = 0; r < 4; ++r) {
                    a_lds[0][w * 16 + lg * 4 + r] =
                        f2bf(__builtin_amdgcn_rcpf(fmaxf(r0[r], SMIN)));
                    a_lds[1][w * 16 + lg * 4 + r] =
                        f2bf(__builtin_amdgcn_rcpf(fmaxf(r1[r], SMIN)));
                }
            }
            __syncthreads();
        }
    }

    // ---- epilogue: out = E * a_m * b_n (both matrices) ----
#pragma unroll
    for (int pm = 0; pm < 2; ++pm) {
        float* dst = out + mat0 + ((size_t)pm << 14) + (size_t)M * 128 + lg * 8;
        const float av = bf2f(a_lds[pm][M]);
#pragma unroll
        for (int c = 0; c < 4; ++c) {
            const bf16x8 e = af[pm][c];
            const bf16x8 bop = *(const bf16x8*)&b_lds[pm][c * 32 + lg * 8];
            float4 o0, o1;
            o0.x = bf2f((u16)e[0]) * av * bf2f((u16)bop[0]);
            o0.y = bf2f((u16)e[1]) * av * bf2f((u16)bop[1]);
            o0.z = bf2f((u16)e[2]) * av * bf2f((u16)bop[2]);
            o0.w = bf2f((u16)e[3]) * av * bf2f((u16)bop[3]);
            o1.x = bf2f((u16)e[4]) * av * bf2f((u16)bop[4]);
            o1.y = bf2f((u16)e[5]) * av * bf2f((u16)bop[5]);
            o1.z = bf2f((u16)e[6]) * av * bf2f((u16)bop[6]);
            o1.w = bf2f((u16)e[7]) * av * bf2f((u16)bop[7]);
            *(float4*)(dst + c * 32)     = o0;
            *(float4*)(dst + c * 32 + 4) = o1;
        }
    }
}

extern "C" void kernel_launch(void* const* d_in, const int* in_sizes, int n_in,
                              void* d_out, int out_size, void* d_ws, size_t ws_size,
                              hipStream_t stream) {
    (void)n_in; (void)d_ws; (void)ws_size; (void)out_size;
    const float* in  = (const float*)d_in[0];
    float*       out = (float*)d_out;
    const int n_mat = in_sizes[0] / (128 * 128);  // 4096
    sinkhorn_kernel<<<dim3(n_mat / 2), dim3(512), 0, stream>>>(in, out);
}